// Round 1
// 876.519 us; speedup vs baseline: 1.0859x; 1.0859x over previous
//
#include <hip/hip_runtime.h>
#include <stdint.h>

#define CANDS 32768
#define HID   1024
#define KDIM  4096
#define NREL  10

typedef __attribute__((ext_vector_type(8))) short bf16x8;   // 8 bf16 = 4 VGPRs
typedef __attribute__((ext_vector_type(4))) float f32x4;

__device__ __forceinline__ float bf2f(unsigned short u) {
  union { unsigned int i; float f; } v; v.i = ((unsigned int)u) << 16; return v.f;
}
__device__ __forceinline__ unsigned short f2bf(float f) {
  union { float f; unsigned int i; } v; v.f = f;
  unsigned int x = v.i;
  return (unsigned short)((x + 0x7FFFu + ((x >> 16) & 1u)) >> 16);  // RNE
}
// async global->LDS, 16B per lane. LDS dest must be wave-uniform base + lane*16.
__device__ __forceinline__ void async16(const void* g, void* l) {
  __builtin_amdgcn_global_load_lds(
      (const __attribute__((address_space(1))) unsigned int*)(uintptr_t)g,
      (__attribute__((address_space(3))) unsigned int*)(uintptr_t)l,
      16, 0, 0);
}

// ---------- kernel 1: W1 fp32 [4096][1024] -> W1T bf16 [1024][4096] ----------
__global__ void transpose_w1(const float* __restrict__ W1,
                             unsigned short* __restrict__ W1T) {
  __shared__ __align__(16) unsigned short tile[64][72];  // +8 pad breaks bank conflicts
  int bk = blockIdx.x;            // 64 tiles along K=4096
  int bn = blockIdx.y;            // 16 tiles along N=1024
  int t = threadIdx.x;            // 256
  int r = t >> 3, c8 = (t & 7) * 8;
  for (int i = 0; i < 2; ++i) {
    int rr = r + i * 32;
    const float4* src = (const float4*)(W1 + (size_t)(bk * 64 + rr) * HID + bn * 64 + c8);
    float4 v0 = src[0], v1 = src[1];
    tile[rr][c8 + 0] = f2bf(v0.x); tile[rr][c8 + 1] = f2bf(v0.y);
    tile[rr][c8 + 2] = f2bf(v0.z); tile[rr][c8 + 3] = f2bf(v0.w);
    tile[rr][c8 + 4] = f2bf(v1.x); tile[rr][c8 + 5] = f2bf(v1.y);
    tile[rr][c8 + 6] = f2bf(v1.z); tile[rr][c8 + 7] = f2bf(v1.w);
  }
  __syncthreads();
  for (int i = 0; i < 2; ++i) {
    int rr = r + i * 32;
    unsigned short tmp[8];
    for (int j = 0; j < 8; ++j) tmp[j] = tile[c8 + j][rr];
    ushort4* dst = (ushort4*)(W1T + (size_t)(bn * 64 + rr) * KDIM + bk * 64 + c8);
    dst[0] = *(ushort4*)&tmp[0];
    dst[1] = *(ushort4*)&tmp[4];
  }
}

// ----- kernel 2: gather fp32 emb + build feats [32768][4096] bf16 -----
__global__ __launch_bounds__(256) void build_feats(
    const float* __restrict__ emb,
    const int* __restrict__ sidx,
    const int* __restrict__ didx,
    unsigned short* __restrict__ feats) {
  int t = threadIdx.x;  // 256 threads x 4 elems = 1024 (one row per iter)
  for (int m = blockIdx.x; m < CANDS; m += gridDim.x) {
    const float* srow = emb + (size_t)sidx[m] * HID;
    const float* drow = emb + (size_t)didx[m] * HID;
    float4 s4 = *(const float4*)(srow + t * 4);
    float4 d4 = *(const float4*)(drow + t * 4);
    unsigned short* o = feats + (size_t)m * KDIM;
    ushort4 sv, dv, av, pv;
    sv.x = f2bf(s4.x); sv.y = f2bf(s4.y); sv.z = f2bf(s4.z); sv.w = f2bf(s4.w);
    dv.x = f2bf(d4.x); dv.y = f2bf(d4.y); dv.z = f2bf(d4.z); dv.w = f2bf(d4.w);
    av.x = f2bf(fabsf(s4.x - d4.x)); av.y = f2bf(fabsf(s4.y - d4.y));
    av.z = f2bf(fabsf(s4.z - d4.z)); av.w = f2bf(fabsf(s4.w - d4.w));
    pv.x = f2bf(s4.x * d4.x); pv.y = f2bf(s4.y * d4.y);
    pv.z = f2bf(s4.z * d4.z); pv.w = f2bf(s4.w * d4.w);
    *(ushort4*)(o + t * 4)           = sv;
    *(ushort4*)(o + HID + t * 4)     = dv;
    *(ushort4*)(o + 2 * HID + t * 4) = av;
    *(ushort4*)(o + 3 * HID + t * 4) = pv;
  }
}

// -------- kernel 3: GEMM1 feats[32768x4096] @ W1T^T -> GELU -> H[32768x1024] bf16 --------
// 256x256 tile, BK=64, 8 waves (2M x 4N), 128 KiB double-buffered LDS.
// T1: XCD-aware block swizzle (512 % 8 == 0, simple form bijective).
// T2: XOR bank-swizzle, both-sides (pre-swizzled global source + swizzled ds_read).
// T4: counted s_waitcnt vmcnt(8) — next tile's 8 stages stay in flight across barriers.
// T5: s_setprio(1) around the MFMA cluster.
// Sync invariants: 2 barriers per K-tile. Stage(kt+1) writes buf[c^1], whose last
// reads (iter kt-1) finished before the previous end-barrier. vmcnt(8) waits exactly
// the 8 older stages of tile kt (vmcnt counts complete in issue order, so extra VMEM
// ops only make the wait stricter, never unsafe).
#define G1_BM 256
#define G1_BN 256
#define G1_BK 64
#define G1_NT (KDIM / G1_BK)   // 64 K-tiles

__global__ __launch_bounds__(512, 2) void gemm1_gelu(
    const unsigned short* __restrict__ A,   // feats [M][4096] bf16
    const unsigned short* __restrict__ BT,  // W1T   [1024][4096] bf16
    const float* __restrict__ b1,           // [1024] fp32
    unsigned short* __restrict__ H) {       // [M][1024] bf16
  extern __shared__ __align__(16) unsigned short smem[];  // 2 x (A 16384 + B 16384) shorts = 128 KiB

  int bid = blockIdx.x;                     // 512 blocks
  int wg  = (bid & 7) * 64 + (bid >> 3);    // XCD-contiguous chunks, n fastest
  int m0 = (wg >> 2) * G1_BM;               // 128 M-tiles
  int n0 = (wg & 3) * G1_BN;                // 4 N-tiles (A-panel L2 reuse)

  int t = threadIdx.x;
  int lane = t & 63, w = t >> 6;
  int wm = w >> 2, wn = w & 3;              // wave grid 2M x 4N; per-wave C = 128x64
  int quad = lane >> 4, l16 = lane & 15;

  // ---- staging constants (lane-linear LDS dest; swizzle applied to GLOBAL src) ----
  // load l of matrix X covers rows l*64+tr, slot = t&7; LDS holds global k-slot
  // (slot ^ (row&7)) at (row, slot): XOR involution, row&7 == tr&7 for all l.
  int tr = t >> 3;                          // 0..63
  int slot = t & 7;
  int gk8 = (slot ^ (tr & 7)) * 8;          // swizzled k element offset within BK=64
  const unsigned short* gA = A  + (size_t)(m0 + tr) * KDIM + gk8;
  const unsigned short* gB = BT + (size_t)(n0 + tr) * KDIM + gk8;
  int lidx = t * 8;                         // shorts; byte = t*16 (wave base + lane*16)

  // ---- fragment-read constants (swizzled ds_read: slot (4h+quad) ^ (l16&7)) ----
  int sx = l16 & 7;
  int aoff = (wm * 128 + l16) * G1_BK + ((quad ^ sx) * 8);
  int boff = (wn * 64  + l16) * G1_BK + ((quad ^ sx) * 8);

  f32x4 acc[8][4] = {};

#define G1_STAGE(b, kkelem) do {                                               \
    unsigned short* la_ = smem + (b) * 32768;                                  \
    unsigned short* lb_ = la_ + 16384;                                         \
    _Pragma("unroll")                                                          \
    for (int l_ = 0; l_ < 4; ++l_)                                             \
      async16(gA + (size_t)l_ * 64 * KDIM + (kkelem), la_ + l_ * 4096 + lidx); \
    _Pragma("unroll")                                                          \
    for (int l_ = 0; l_ < 4; ++l_)                                             \
      async16(gB + (size_t)l_ * 64 * KDIM + (kkelem), lb_ + l_ * 4096 + lidx); \
  } while (0)

  G1_STAGE(0, 0);                            // prologue: tile 0 -> buf0
  for (int kt = 0; kt < G1_NT; ++kt) {
    int c = kt & 1;
    if (kt + 1 < G1_NT) {
      G1_STAGE(c ^ 1, (kt + 1) * G1_BK);     // issue next tile FIRST (full-iter cover)
      asm volatile("s_waitcnt vmcnt(8)" ::: "memory");   // wait only tile kt's stages
    } else {
      asm volatile("s_waitcnt vmcnt(0)" ::: "memory");
    }
    __builtin_amdgcn_s_barrier();            // all waves' tile-kt stages landed
    asm volatile("" ::: "memory");
    const unsigned short* bufA = smem + c * 32768;
    const unsigned short* bufB = bufA + 16384;
    __builtin_amdgcn_s_setprio(1);
#pragma unroll
    for (int h = 0; h < 2; ++h) {            // K=64 -> two 16x16x32 k-halves
      bf16x8 bfr[4], afr[8];
#pragma unroll
      for (int j = 0; j < 4; ++j)
        bfr[j] = *(const bf16x8*)&bufB[(boff ^ (h << 5)) + j * 1024];
#pragma unroll
      for (int i = 0; i < 8; ++i)
        afr[i] = *(const bf16x8*)&bufA[(aoff ^ (h << 5)) + i * 1024];
#pragma unroll
      for (int i = 0; i < 8; ++i)
#pragma unroll
        for (int j = 0; j < 4; ++j)
          acc[i][j] = __builtin_amdgcn_mfma_f32_16x16x32_bf16(afr[i], bfr[j], acc[i][j], 0, 0, 0);
    }
    __builtin_amdgcn_s_setprio(0);
    asm volatile("" ::: "memory");
    __builtin_amdgcn_s_barrier();            // reads of buf[c] done before next iter overwrites it
  }

  // epilogue: bias + exact GELU, store bf16
#pragma unroll
  for (int j = 0; j < 4; ++j) {
    int n = n0 + wn * 64 + j * 16 + l16;
    float bias = b1[n];
#pragma unroll
    for (int i = 0; i < 8; ++i) {
#pragma unroll
      for (int r = 0; r < 4; ++r) {
        int m = m0 + wm * 128 + i * 16 + quad * 4 + r;
        float x = acc[i][j][r] + bias;
        float g = 0.5f * x * (1.0f + erff(x * 0.70710678118654752f));
        H[(size_t)m * HID + n] = f2bf(g);
      }
    }
  }
#undef G1_STAGE
}

// ---- kernel 4: GEMM2 (H @ W2 + b2), log_softmax, fp32 logits store, loss partial ----
__global__ __launch_bounds__(256) void gemm2_loss(
    const unsigned short* __restrict__ H,    // [32768][1024] bf16
    const float* __restrict__ W2,            // [1024][10] fp32
    const float* __restrict__ b2,            // [10] fp32
    const int* __restrict__ labels,          // [32768]
    float* __restrict__ out,                 // out[0]=loss, out[1..]=logits fp32
    float* __restrict__ gacc) {
#define W2P 1032   // pitch in shorts: 2064B = 16B-aligned
  __shared__ __align__(16) unsigned short w2t[16 * W2P];
  __shared__ float lacc;
  int t = threadIdx.x;
  int lane = t & 63, wave = t >> 6;
  int quad = lane >> 4, l16 = lane & 15;
  if (t == 0) lacc = 0.0f;
  for (int k = t; k < HID; k += 256) {
    for (int j = 0; j < NREL; ++j) w2t[j * W2P + k] = f2bf(W2[(size_t)k * NREL + j]);
    for (int j = NREL; j < 16; ++j) w2t[j * W2P + k] = 0;
  }
  __syncthreads();

  int r0 = blockIdx.x * 64 + wave * 16;
  const unsigned short* hrow = H + (size_t)(r0 + l16) * HID;
  f32x4 acc = {};
#pragma unroll 8
  for (int s = 0; s < 32; ++s) {
    bf16x8 a = *(const bf16x8*)(hrow + s * 32 + quad * 8);
    bf16x8 b = *(const bf16x8*)&w2t[l16 * W2P + s * 32 + quad * 8];
    acc = __builtin_amdgcn_mfma_f32_16x16x32_bf16(a, b, acc, 0, 0, 0);
  }

  int col = l16;
  float bias = (col < NREL) ? b2[col] : 0.0f;
  float local = 0.0f;
#pragma unroll
  for (int r = 0; r < 4; ++r) {
    int row = r0 + quad * 4 + r;
    float x = acc[r] + bias;
    float v = (col < NREL) ? x : -1e30f;
    float mx = v;
    for (int d = 1; d < 16; d <<= 1) mx = fmaxf(mx, __shfl_xor(mx, d));
    float e = (col < NREL) ? expf(x - mx) : 0.0f;
    float se = e;
    for (int d = 1; d < 16; d <<= 1) se += __shfl_xor(se, d);
    float lse = mx + logf(se);
    if (col < NREL) {
      out[1 + (size_t)row * NREL + col] = x;
      if (labels[row] == col) local += (lse - x);   // -logp
    }
  }
  atomicAdd(&lacc, local);
  __syncthreads();
  if (t == 0) atomicAdd(gacc, lacc);
}

__global__ void finalize_loss(const float* __restrict__ gacc, float* __restrict__ out) {
  out[0] = *gacc * (1.0f / (float)CANDS);
}

extern "C" void kernel_launch(void* const* d_in, const int* in_sizes, int n_in,
                              void* d_out, int out_size, void* d_ws, size_t ws_size,
                              hipStream_t stream) {
  const float* emb    = (const float*)d_in[0];
  const int*   sidx   = (const int*)d_in[1];
  const int*   didx   = (const int*)d_in[2];
  const int*   labels = (const int*)d_in[3];
  const float* W1     = (const float*)d_in[4];
  const float* b1     = (const float*)d_in[5];
  const float* W2     = (const float*)d_in[6];
  const float* b2     = (const float*)d_in[7];
  float* out = (float*)d_out;

  char* ws = (char*)d_ws;
  float*          gacc  = (float*)ws;                                        // 4 B
  unsigned short* W1T   = (unsigned short*)(ws + 256);                       // 8 MB
  unsigned short* feats = (unsigned short*)(ws + 256 + 8388608);             // 256 MB
  unsigned short* H     = (unsigned short*)(ws + 256 + 8388608 + 268435456); // 64 MB

  static bool g1_attr_set = false;
  if (!g1_attr_set) {
    // opt-in for 128 KiB dynamic LDS (gfx950 has 160 KiB/CU); not a stream op,
    // safe under graph capture. Ignore return (no-op where not required).
    (void)hipFuncSetAttribute((const void*)gemm1_gelu,
                              hipFuncAttributeMaxDynamicSharedMemorySize, 131072);
    g1_attr_set = true;
  }

  hipMemsetAsync(gacc, 0, sizeof(float), stream);
  transpose_w1<<<dim3(64, 16), 256, 0, stream>>>(W1, W1T);
  build_feats<<<2048, 256, 0, stream>>>(emb, sidx, didx, feats);
  gemm1_gelu<<<512, 512, 131072, stream>>>(feats, W1T, b1, H);
  gemm2_loss<<<CANDS / 64, 256, 0, stream>>>(H, W2, b2, labels, out, gacc);
  finalize_loss<<<1, 1, 0, stream>>>(gacc, out);
}

// Round 2
// 819.727 us; speedup vs baseline: 1.1611x; 1.0693x over previous
//
#include <hip/hip_runtime.h>
#include <stdint.h>

#define CANDS 32768
#define HID   1024
#define KDIM  4096
#define NREL  10

typedef __attribute__((ext_vector_type(8))) short bf16x8;   // 8 bf16 = 4 VGPRs
typedef __attribute__((ext_vector_type(4))) float f32x4;

__device__ __forceinline__ float bf2f(unsigned short u) {
  union { unsigned int i; float f; } v; v.i = ((unsigned int)u) << 16; return v.f;
}
__device__ __forceinline__ unsigned short f2bf(float f) {
  union { float f; unsigned int i; } v; v.f = f;
  unsigned int x = v.i;
  return (unsigned short)((x + 0x7FFFu + ((x >> 16) & 1u)) >> 16);  // RNE
}
// async global->LDS, 16B per lane. LDS dest must be wave-uniform base + lane*16.
__device__ __forceinline__ void async16(const void* g, void* l) {
  __builtin_amdgcn_global_load_lds(
      (const __attribute__((address_space(1))) unsigned int*)(uintptr_t)g,
      (__attribute__((address_space(3))) unsigned int*)(uintptr_t)l,
      16, 0, 0);
}

// ---------- kernel 1: W1 fp32 [4096][1024] -> W1T bf16 [1024][4096] ----------
__global__ void transpose_w1(const float* __restrict__ W1,
                             unsigned short* __restrict__ W1T) {
  __shared__ __align__(16) unsigned short tile[64][72];  // +8 pad breaks bank conflicts
  int bk = blockIdx.x;            // 64 tiles along K=4096
  int bn = blockIdx.y;            // 16 tiles along N=1024
  int t = threadIdx.x;            // 256
  int r = t >> 3, c8 = (t & 7) * 8;
  for (int i = 0; i < 2; ++i) {
    int rr = r + i * 32;
    const float4* src = (const float4*)(W1 + (size_t)(bk * 64 + rr) * HID + bn * 64 + c8);
    float4 v0 = src[0], v1 = src[1];
    tile[rr][c8 + 0] = f2bf(v0.x); tile[rr][c8 + 1] = f2bf(v0.y);
    tile[rr][c8 + 2] = f2bf(v0.z); tile[rr][c8 + 3] = f2bf(v0.w);
    tile[rr][c8 + 4] = f2bf(v1.x); tile[rr][c8 + 5] = f2bf(v1.y);
    tile[rr][c8 + 6] = f2bf(v1.z); tile[rr][c8 + 7] = f2bf(v1.w);
  }
  __syncthreads();
  for (int i = 0; i < 2; ++i) {
    int rr = r + i * 32;
    unsigned short tmp[8];
    for (int j = 0; j < 8; ++j) tmp[j] = tile[c8 + j][rr];
    ushort4* dst = (ushort4*)(W1T + (size_t)(bn * 64 + rr) * KDIM + bk * 64 + c8);
    dst[0] = *(ushort4*)&tmp[0];
    dst[1] = *(ushort4*)&tmp[4];
  }
}

// ----- kernel 2: gather fp32 emb + build feats [32768][4096] bf16 -----
__global__ __launch_bounds__(256) void build_feats(
    const float* __restrict__ emb,
    const int* __restrict__ sidx,
    const int* __restrict__ didx,
    unsigned short* __restrict__ feats) {
  int t = threadIdx.x;  // 256 threads x 4 elems = 1024 (one row per iter)
  for (int m = blockIdx.x; m < CANDS; m += gridDim.x) {
    const float* srow = emb + (size_t)sidx[m] * HID;
    const float* drow = emb + (size_t)didx[m] * HID;
    float4 s4 = *(const float4*)(srow + t * 4);
    float4 d4 = *(const float4*)(drow + t * 4);
    unsigned short* o = feats + (size_t)m * KDIM;
    ushort4 sv, dv, av, pv;
    sv.x = f2bf(s4.x); sv.y = f2bf(s4.y); sv.z = f2bf(s4.z); sv.w = f2bf(s4.w);
    dv.x = f2bf(d4.x); dv.y = f2bf(d4.y); dv.z = f2bf(d4.z); dv.w = f2bf(d4.w);
    av.x = f2bf(fabsf(s4.x - d4.x)); av.y = f2bf(fabsf(s4.y - d4.y));
    av.z = f2bf(fabsf(s4.z - d4.z)); av.w = f2bf(fabsf(s4.w - d4.w));
    pv.x = f2bf(s4.x * d4.x); pv.y = f2bf(s4.y * d4.y);
    pv.z = f2bf(s4.z * d4.z); pv.w = f2bf(s4.w * d4.w);
    *(ushort4*)(o + t * 4)           = sv;
    *(ushort4*)(o + HID + t * 4)     = dv;
    *(ushort4*)(o + 2 * HID + t * 4) = av;
    *(ushort4*)(o + 3 * HID + t * 4) = pv;
  }
}

// -------- kernel 3: GEMM1 feats[32768x4096] @ W1T^T -> GELU -> H[32768x1024] bf16 --------
// 256x256 tile, BK=64, 8 waves (2M x 4N), 128 KiB LDS, static buffers:
// even K-tiles -> buf0, odd -> buf1.
// 8-phase schedule (T3+T4): per 2-K-tile iter, 8 phases of
//   {ds_read quadrant frags | stage one half-tile granule -> barrier ->
//    lgkmcnt(0) -> setprio(1) -> 16 MFMA -> setprio(0) -> barrier}.
// Stage slots (solved vs region freeing):  ph0: A(kt+1)->buf1 (buf1.A freed by
// prev ph7 barrier); ph1/ph2: B(kt+2)->buf0 (buf0.B freed after ph0);
// ph4: A(kt+2)->buf0 (buf0.A freed after ph3); ph5/ph6: B(kt+3)->buf1.
// Counted waits ONLY at ph3-end / ph7-end: vmcnt(4) = next tile's 4 B-loads stay
// in flight across the barrier (in-order vmcnt => everything older has landed).
// Last-iter edge: skipped stages collapse the count -> vmcnt(0) at ph3.
#define G1_BM 256
#define G1_BN 256
#define G1_BK 64
#define G1_NT (KDIM / G1_BK)   // 64 K-tiles

__global__ __launch_bounds__(512, 2) void gemm1_gelu(
    const unsigned short* __restrict__ A,   // feats [M][4096] bf16
    const unsigned short* __restrict__ BT,  // W1T   [1024][4096] bf16
    const float* __restrict__ b1,           // [1024] fp32
    unsigned short* __restrict__ H) {       // [M][1024] bf16
  extern __shared__ __align__(16) unsigned short smem[];  // 128 KiB

  int bid = blockIdx.x;                     // 512 blocks
  int wg  = (bid & 7) * 64 + (bid >> 3);    // XCD-contiguous chunks, n fastest
  int m0 = (wg >> 2) * G1_BM;               // 128 M-tiles
  int n0 = (wg & 3) * G1_BN;                // 4 N-tiles (A-panel L2 reuse)

  int t = threadIdx.x;
  int lane = t & 63, w = t >> 6;
  int wm = w >> 2, wn = w & 3;              // wave grid 2M x 4N; per-wave C = 128x64
  int quad = lane >> 4, l16 = lane & 15;

  // ---- staging constants (lane-linear LDS dest; swizzle applied to GLOBAL src) ----
  int tr = t >> 3;                          // 0..63
  int slot = t & 7;
  int gk8 = (slot ^ (tr & 7)) * 8;          // swizzled k element offset within BK=64
  const unsigned short* gA = A  + (size_t)(m0 + tr) * KDIM + gk8;
  const unsigned short* gB = BT + (size_t)(n0 + tr) * KDIM + gk8;
  int lidx = t * 8;                         // shorts; byte = t*16 (wave base + lane*16)

  // ---- fragment-read constants (swizzled ds_read: slot (4h+quad) ^ (l16&7)) ----
  int sx = l16 & 7;
  int aoff = (wm * 128 + l16) * G1_BK + ((quad ^ sx) * 8);
  int boff = (wn * 64  + l16) * G1_BK + ((quad ^ sx) * 8);

  unsigned short* bufA0 = smem;             // 16384 shorts each
  unsigned short* bufB0 = smem + 16384;
  unsigned short* bufA1 = smem + 32768;
  unsigned short* bufB1 = smem + 49152;

  f32x4 acc[8][4] = {};
  bf16x8 bfr[4][2];   // persistent across a K-tile's 4 phases
  bf16x8 af[2][2];    // per-phase A fragments

#define STG_A(DST, ktile) do { _Pragma("unroll")                                 \
    for (int l_ = 0; l_ < 4; ++l_)                                               \
      async16(gA + (size_t)l_ * 64 * KDIM + (ktile) * G1_BK,                     \
              (DST) + l_ * 4096 + lidx); } while (0)
#define STG_BLO(DST, ktile) do { _Pragma("unroll")                               \
    for (int l_ = 0; l_ < 2; ++l_)                                               \
      async16(gB + (size_t)l_ * 64 * KDIM + (ktile) * G1_BK,                     \
              (DST) + l_ * 4096 + lidx); } while (0)
#define STG_BHI(DST, ktile) do { _Pragma("unroll")                               \
    for (int l_ = 2; l_ < 4; ++l_)                                               \
      async16(gB + (size_t)l_ * 64 * KDIM + (ktile) * G1_BK,                     \
              (DST) + l_ * 4096 + lidx); } while (0)

// phase: ds_read quadrant (and B on LOADB) | stage (__VA_ARGS__) | barrier |
//        lgkmcnt(0) | setprio(1) 16x MFMA setprio(0) | TAILWAIT | barrier
#define PHASE(qq, AB, BB, LOADB, TAILWAIT, ...) do {                             \
    if (LOADB) {                                                                 \
      _Pragma("unroll") for (int j_ = 0; j_ < 4; ++j_)                           \
        _Pragma("unroll") for (int h_ = 0; h_ < 2; ++h_)                         \
          bfr[j_][h_] = *(const bf16x8*)&(BB)[(boff ^ (h_ << 5)) + j_ * 1024];   \
    }                                                                            \
    _Pragma("unroll") for (int i_ = 0; i_ < 2; ++i_)                             \
      _Pragma("unroll") for (int h_ = 0; h_ < 2; ++h_)                           \
        af[i_][h_] = *(const bf16x8*)&(AB)[(aoff ^ (h_ << 5)) + (2*(qq)+i_) * 1024]; \
    __VA_ARGS__;                                                                 \
    asm volatile("" ::: "memory");                                               \
    __builtin_amdgcn_s_barrier();                                                \
    asm volatile("s_waitcnt lgkmcnt(0)" ::: "memory");                           \
    __builtin_amdgcn_sched_barrier(0);                                           \
    __builtin_amdgcn_s_setprio(1);                                               \
    _Pragma("unroll") for (int h_ = 0; h_ < 2; ++h_)                             \
      _Pragma("unroll") for (int i_ = 0; i_ < 2; ++i_)                           \
        _Pragma("unroll") for (int j_ = 0; j_ < 4; ++j_)                         \
          acc[2*(qq)+i_][j_] = __builtin_amdgcn_mfma_f32_16x16x32_bf16(          \
              af[i_][h_], bfr[j_][h_], acc[2*(qq)+i_][j_], 0, 0, 0);             \
    __builtin_amdgcn_s_setprio(0);                                               \
    TAILWAIT;                                                                    \
    asm volatile("" ::: "memory");                                               \
    __builtin_amdgcn_s_barrier();                                                \
    asm volatile("" ::: "memory");                                               \
  } while (0)

#define W_PH3 do { if (kt + 2 < G1_NT)                                           \
      asm volatile("s_waitcnt vmcnt(4)" ::: "memory");                           \
    else asm volatile("s_waitcnt vmcnt(0)" ::: "memory"); } while (0)
#define W_PH7 do { if (kt + 2 < G1_NT)                                           \
      asm volatile("s_waitcnt vmcnt(4)" ::: "memory"); } while (0)
#define W_NONE do {} while (0)

  // prologue: A(0),B(0) then B(1)  (issue order matters for vmcnt(4))
  STG_A(bufA0, 0);
  STG_BLO(bufB0, 0); STG_BHI(bufB0, 0);
  STG_BLO(bufB1, 1); STG_BHI(bufB1, 1);
  asm volatile("s_waitcnt vmcnt(4)" ::: "memory");   // A(0),B(0) landed; B(1) in flight
  asm volatile("" ::: "memory");
  __builtin_amdgcn_s_barrier();
  asm volatile("" ::: "memory");

  for (int kt = 0; kt < G1_NT; kt += 2) {
    // K-tile kt (buf0), quadrants 0-3
    PHASE(0, bufA0, bufB0, 1, W_NONE, STG_A(bufA1, kt + 1));
    PHASE(1, bufA0, bufB0, 0, W_NONE, if (kt + 2 < G1_NT) STG_BLO(bufB0, kt + 2));
    PHASE(2, bufA0, bufB0, 0, W_NONE, if (kt + 2 < G1_NT) STG_BHI(bufB0, kt + 2));
    PHASE(3, bufA0, bufB0, 0, W_PH3, );
    // K-tile kt+1 (buf1), quadrants 0-3
    PHASE(0, bufA1, bufB1, 1, W_NONE, if (kt + 2 < G1_NT) STG_A(bufA0, kt + 2));
    PHASE(1, bufA1, bufB1, 0, W_NONE, if (kt + 3 < G1_NT) STG_BLO(bufB1, kt + 3));
    PHASE(2, bufA1, bufB1, 0, W_NONE, if (kt + 3 < G1_NT) STG_BHI(bufB1, kt + 3));
    PHASE(3, bufA1, bufB1, 0, W_PH7, );
  }

  // epilogue: bias + exact GELU, store bf16
#pragma unroll
  for (int j = 0; j < 4; ++j) {
    int n = n0 + wn * 64 + j * 16 + l16;
    float bias = b1[n];
#pragma unroll
    for (int i = 0; i < 8; ++i) {
#pragma unroll
      for (int r = 0; r < 4; ++r) {
        int m = m0 + wm * 128 + i * 16 + quad * 4 + r;
        float x = acc[i][j][r] + bias;
        float g = 0.5f * x * (1.0f + erff(x * 0.70710678118654752f));
        H[(size_t)m * HID + n] = f2bf(g);
      }
    }
  }
#undef STG_A
#undef STG_BLO
#undef STG_BHI
#undef PHASE
#undef W_PH3
#undef W_PH7
#undef W_NONE
}

// ---- kernel 4: GEMM2 (H @ W2 + b2), log_softmax, fp32 logits store, loss partial ----
__global__ __launch_bounds__(256) void gemm2_loss(
    const unsigned short* __restrict__ H,    // [32768][1024] bf16
    const float* __restrict__ W2,            // [1024][10] fp32
    const float* __restrict__ b2,            // [10] fp32
    const int* __restrict__ labels,          // [32768]
    float* __restrict__ out,                 // out[0]=loss, out[1..]=logits fp32
    float* __restrict__ gacc) {
#define W2P 1032   // pitch in shorts: 2064B = 16B-aligned
  __shared__ __align__(16) unsigned short w2t[16 * W2P];
  __shared__ float lacc;
  int t = threadIdx.x;
  int lane = t & 63, wave = t >> 6;
  int quad = lane >> 4, l16 = lane & 15;
  if (t == 0) lacc = 0.0f;
  for (int k = t; k < HID; k += 256) {
    for (int j = 0; j < NREL; ++j) w2t[j * W2P + k] = f2bf(W2[(size_t)k * NREL + j]);
    for (int j = NREL; j < 16; ++j) w2t[j * W2P + k] = 0;
  }
  __syncthreads();

  int r0 = blockIdx.x * 64 + wave * 16;
  const unsigned short* hrow = H + (size_t)(r0 + l16) * HID;
  f32x4 acc = {};
#pragma unroll 8
  for (int s = 0; s < 32; ++s) {
    bf16x8 a = *(const bf16x8*)(hrow + s * 32 + quad * 8);
    bf16x8 b = *(const bf16x8*)&w2t[l16 * W2P + s * 32 + quad * 8];
    acc = __builtin_amdgcn_mfma_f32_16x16x32_bf16(a, b, acc, 0, 0, 0);
  }

  int col = l16;
  float bias = (col < NREL) ? b2[col] : 0.0f;
  float local = 0.0f;
#pragma unroll
  for (int r = 0; r < 4; ++r) {
    int row = r0 + quad * 4 + r;
    float x = acc[r] + bias;
    float v = (col < NREL) ? x : -1e30f;
    float mx = v;
    for (int d = 1; d < 16; d <<= 1) mx = fmaxf(mx, __shfl_xor(mx, d));
    float e = (col < NREL) ? expf(x - mx) : 0.0f;
    float se = e;
    for (int d = 1; d < 16; d <<= 1) se += __shfl_xor(se, d);
    float lse = mx + logf(se);
    if (col < NREL) {
      out[1 + (size_t)row * NREL + col] = x;
      if (labels[row] == col) local += (lse - x);   // -logp
    }
  }
  atomicAdd(&lacc, local);
  __syncthreads();
  if (t == 0) atomicAdd(gacc, lacc);
}

__global__ void finalize_loss(const float* __restrict__ gacc, float* __restrict__ out) {
  out[0] = *gacc * (1.0f / (float)CANDS);
}

extern "C" void kernel_launch(void* const* d_in, const int* in_sizes, int n_in,
                              void* d_out, int out_size, void* d_ws, size_t ws_size,
                              hipStream_t stream) {
  const float* emb    = (const float*)d_in[0];
  const int*   sidx   = (const int*)d_in[1];
  const int*   didx   = (const int*)d_in[2];
  const int*   labels = (const int*)d_in[3];
  const float* W1     = (const float*)d_in[4];
  const float* b1     = (const float*)d_in[5];
  const float* W2     = (const float*)d_in[6];
  const float* b2     = (const float*)d_in[7];
  float* out = (float*)d_out;

  char* ws = (char*)d_ws;
  float*          gacc  = (float*)ws;                                        // 4 B
  unsigned short* W1T   = (unsigned short*)(ws + 256);                       // 8 MB
  unsigned short* feats = (unsigned short*)(ws + 256 + 8388608);             // 256 MB
  unsigned short* H     = (unsigned short*)(ws + 256 + 8388608 + 268435456); // 64 MB

  static bool g1_attr_set = false;
  if (!g1_attr_set) {
    (void)hipFuncSetAttribute((const void*)gemm1_gelu,
                              hipFuncAttributeMaxDynamicSharedMemorySize, 131072);
    g1_attr_set = true;
  }

  hipMemsetAsync(gacc, 0, sizeof(float), stream);
  transpose_w1<<<dim3(64, 16), 256, 0, stream>>>(W1, W1T);
  build_feats<<<2048, 256, 0, stream>>>(emb, sidx, didx, feats);
  gemm1_gelu<<<512, 512, 131072, stream>>>(feats, W1T, b1, H);
  gemm2_loss<<<CANDS / 64, 256, 0, stream>>>(H, W2, b2, labels, out, gacc);
  finalize_loss<<<1, 1, 0, stream>>>(gacc, out);
}